// Round 4
// baseline (183.237 us; speedup 1.0000x reference)
//
#include <hip/hip_runtime.h>

// APMLSparse: B=4, N=M=4096, D=3.
// loss = sum_rows sum_{kept j} p_ij * d_ij, p = softmax_j(-d_i),
// kept = descending-p prefix until cumulative mass >= P_MIN = 0.8.
//
// R11: VALU-issue-bound model (VALUBusy*dur invariant across R7-R10).
// Only lever: delete instructions. Changes vs R10:
//  1. Phase B FUSED into the dual-threshold pass: one full scan computes
//     exact masses at margin-widened warm thresholds AND compacts the
//     between-band to LDS (band = gl && !gh from the same compares).
//     Deletes the separate compaction pass (~320 VALU/wave).
//     Fast path valid iff widened bracket is a true bracket and band<=256;
//     else full classic fallback (bracket-derive -> 4-chain probes ->
//     classic recompaction). Correctness never depends on sampling.
//  2. Warm-start 5 -> 7 sampled rounds (cheap) so the widened band
//     almost always fits 256.
//  3. pmax/dppMax dropped: pTop = 1.0f (p = exp(-d) < 1; R8/R9-proven).
//  4. C1 dual-threshold rounds (R8-proven dppSum2 scheme); cv[] dropped
//     via thresholds>0 trick (invalid compact slots hold 0.0f).
//  5. Value-critical order UNCHANGED: zl (Z), spd (Phase D), tie logic,
//     probe-mass association (serial chain + dppSum), two-stage reduce.

#define MCOLS 4096
#define KPT   64            // 4096 / 64 lanes
#define WPB   4             // waves per block
#define P_MIN 0.8f
#define CAPS  384           // per-wave scomp stride (256 band + slack)

// ---- DPP wave64 reductions (old=0 => disabled/out-of-range lanes add 0) ----
template <int CTRL, int RM, int BM, bool BC>
__device__ __forceinline__ float dpp_mov0(float x) {
    return __int_as_float(__builtin_amdgcn_update_dpp(
        0, __float_as_int(x), CTRL, RM, BM, BC));
}
__device__ __forceinline__ float dppSum(float v) {
    v += dpp_mov0<0x111, 0xF, 0xF, true >(v);   // row_shr:1
    v += dpp_mov0<0x112, 0xF, 0xF, true >(v);   // row_shr:2
    v += dpp_mov0<0x114, 0xF, 0xF, true >(v);   // row_shr:4
    v += dpp_mov0<0x118, 0xF, 0xF, true >(v);   // row_shr:8
    v += dpp_mov0<0x142, 0xA, 0xF, false>(v);   // row_bcast15 -> rows 1,3
    v += dpp_mov0<0x143, 0xC, 0xF, false>(v);   // row_bcast31 -> rows 2,3
    return __int_as_float(__builtin_amdgcn_readlane(__float_as_int(v), 63));
}
__device__ __forceinline__ void dppSum2(float& a, float& b) {
    a += dpp_mov0<0x111, 0xF, 0xF, true >(a); b += dpp_mov0<0x111, 0xF, 0xF, true >(b);
    a += dpp_mov0<0x112, 0xF, 0xF, true >(a); b += dpp_mov0<0x112, 0xF, 0xF, true >(b);
    a += dpp_mov0<0x114, 0xF, 0xF, true >(a); b += dpp_mov0<0x114, 0xF, 0xF, true >(b);
    a += dpp_mov0<0x118, 0xF, 0xF, true >(a); b += dpp_mov0<0x118, 0xF, 0xF, true >(b);
    a += dpp_mov0<0x142, 0xA, 0xF, false>(a); b += dpp_mov0<0x142, 0xA, 0xF, false>(b);
    a += dpp_mov0<0x143, 0xC, 0xF, false>(a); b += dpp_mov0<0x143, 0xC, 0xF, false>(b);
    a = __int_as_float(__builtin_amdgcn_readlane(__float_as_int(a), 63));
    b = __int_as_float(__builtin_amdgcn_readlane(__float_as_int(b), 63));
}
__device__ __forceinline__ float dppMax(float v) {   // nonneg inputs only
    v = fmaxf(v, dpp_mov0<0x111, 0xF, 0xF, true >(v));
    v = fmaxf(v, dpp_mov0<0x112, 0xF, 0xF, true >(v));
    v = fmaxf(v, dpp_mov0<0x114, 0xF, 0xF, true >(v));
    v = fmaxf(v, dpp_mov0<0x118, 0xF, 0xF, true >(v));
    v = fmaxf(v, dpp_mov0<0x142, 0xA, 0xF, false>(v));
    v = fmaxf(v, dpp_mov0<0x143, 0xC, 0xF, false>(v));
    return __int_as_float(__builtin_amdgcn_readlane(__float_as_int(v), 63));
}

__global__ __launch_bounds__(WPB * 64) void apml_row_wave(
        const float* __restrict__ x, const float* __restrict__ y,
        float* __restrict__ partial, float* __restrict__ out) {
    __shared__ __align__(16) float scomp[WPB * CAPS];
    __shared__ float wacc[WPB];

    const int tid  = threadIdx.x;
    const int wid  = tid >> 6;
    const int lane = tid & 63;
    const int row  = blockIdx.x * WPB + wid;
    const int b    = row >> 12;                 // row / 4096

    const float x0 = x[row * 3 + 0];
    const float x1 = x[row * 3 + 1];
    const float x2 = x[row * 3 + 2];
    const float* yb = y + (size_t)b * MCOLS * 3;

    // ---- setup: p = exp(-d), register-resident; Z via DPP ----
    // zl chain order is value-critical (Z) -> serial, unchanged.
    float p[KPT];
    float zl = 0.0f;
    #pragma unroll
    for (int k = 0; k < KPT; ++k) {
        const int j = k * 64 + lane;
        const float y0 = yb[j * 3 + 0];
        const float y1 = yb[j * 3 + 1];
        const float y2 = yb[j * 3 + 2];
        const float dx = x0 - y0, dy = x1 - y1, dz = x2 - y2;
        const float sq = fmaxf(dx * dx + dy * dy + dz * dz, 1e-12f); // EPS^2
        const float pk = __expf(-sqrtf(sq));
        p[k] = pk;
        zl  += pk;
    }
    const float Z      = dppSum(zl);
    const float target = P_MIN * Z;

    // ---- sampled warm-start: 7 probes on p[0..3] (first 256 elements) ----
    float ssl = 0.0f, ssh = 1.0f;   // p = exp(-d) < 1 strictly
    {
        float eGl = 16.0f * dppSum(p[0] + p[1] + p[2] + p[3]);  // Ghat(0)
        float eGh = 0.0f;
        for (int it = 0; it < 7; ++it) {
            float s;
            if (it & 1) {
                s = 0.5f * (ssl + ssh);
            } else {
                const float den = fmaxf(eGl - eGh, 1e-30f);
                s = ssl + (ssh - ssl) * ((eGl - target) / den);
            }
            if (!(s > ssl && s < ssh)) s = 0.5f * (ssl + ssh);
            if (!(s > ssl && s < ssh)) break;
            float m = 0.0f;
            #pragma unroll
            for (int q = 0; q < 4; ++q) m += (p[q] >= s) ? p[q] : 0.0f;
            m = 16.0f * dppSum(m);
            if (m >= target) { ssl = s; eGl = m; }
            else             { ssh = s; eGh = m; }
        }
    }

    // ---- fused pass: exact masses at margin-widened thresholds AND
    //      band compaction, in ONE full scan ----
    const float ww  = ssh - ssl;
    const float tLo = fmaxf(ssl - 0.75f * ww, 0.0f);
    const float tHi = fminf(ssh + 0.75f * ww, 1.0f);

    float mLo = 0.0f, mHi = 0.0f;
    int   cLo = 0,    cHi = 0,   Cb = 0;
    #pragma unroll
    for (int k = 0; k < KPT; ++k) {
        const float pk = p[k];
        const bool gl = (pk >= tLo);
        const bool gh = (pk >= tHi);
        mLo += gl ? pk : 0.0f;
        mHi += gh ? pk : 0.0f;
        const unsigned long long bl = __ballot(gl);
        const unsigned long long bh = __ballot(gh);
        const unsigned long long bm = bl & ~bh;        // band members
        if (gl && !gh) {
            const unsigned qlo = (unsigned)bm, qhi = (unsigned)(bm >> 32);
            const int within = __builtin_amdgcn_mbcnt_hi(
                                   qhi, __builtin_amdgcn_mbcnt_lo(qlo, 0));
            const int pos = Cb + within;
            if (pos < 256) scomp[wid * CAPS + pos] = pk;
        }
        cLo += (int)__popcll(bl);
        cHi += (int)__popcll(bh);
        Cb  += (int)__popcll(bm);
    }
    dppSum2(mLo, mHi);

    float sl, sh, Gl, Gh;
    int   Cl, Ch, C;
    if (mLo >= target && mHi < target && Cb <= 256) {
        // fast path: widened warm bracket is a true bracket, band compact
        sl = tLo; Gl = mLo; Cl = cLo;
        sh = tHi; Gh = mHi; Ch = cHi;
        C  = Cb;
    } else {
        // ---- fallback: derive bracket from fused results ----
        sl = 0.0f; Gl = Z;    Cl = MCOLS;
        sh = 1.0f; Gh = 0.0f; Ch = 0;
        if (mLo >= target) { sl = tLo; Gl = mLo; Cl = cLo; }
        else               { sh = tLo; Gh = mLo; Ch = cLo; }
        if (mHi >= target) { sl = tHi; Gl = mHi; Cl = cHi; }
        else if (tHi < sh) { sh = tHi; Gh = mHi; Ch = cHi; }

        // classic exact probes (4-chain) until band <= 256
        for (int it = 0; it < 10 && (Cl - Ch) > 256; ++it) {
            float s;
            if (it & 1) {
                s = 0.5f * (sl + sh);
            } else {
                const float den = fmaxf(Gl - Gh, 1e-30f);
                s = sl + (sh - sl) * ((Gl - target) / den);
            }
            if (!(s > sl && s < sh)) s = 0.5f * (sl + sh);
            if (!(s > sl && s < sh)) break;    // ulp-width bracket

            float m0 = 0.0f, m1 = 0.0f, m2 = 0.0f, m3 = 0.0f;
            int   c = 0;
            #pragma unroll
            for (int k = 0; k < KPT; k += 4) {
                const bool g0 = (p[k]     >= s);
                const bool g1 = (p[k + 1] >= s);
                const bool g2 = (p[k + 2] >= s);
                const bool g3 = (p[k + 3] >= s);
                m0 += g0 ? p[k]     : 0.0f; c += (int)__popcll(__ballot(g0));
                m1 += g1 ? p[k + 1] : 0.0f; c += (int)__popcll(__ballot(g1));
                m2 += g2 ? p[k + 2] : 0.0f; c += (int)__popcll(__ballot(g2));
                m3 += g3 ? p[k + 3] : 0.0f; c += (int)__popcll(__ballot(g3));
            }
            const float m = dppSum((m0 + m1) + (m2 + m3));
            if (m >= target) { sl = s; Gl = m; Cl = c; }
            else             { sh = s; Gh = m; Ch = c; }
        }

        // classic re-compaction of band [sl, sh)
        C = 0;
        #pragma unroll
        for (int k = 0; k < KPT; ++k) {
            const bool band = (p[k] >= sl) && (p[k] < sh);
            const unsigned long long mk = __ballot(band);
            if (band) {
                const unsigned qlo = (unsigned)mk, qhi = (unsigned)(mk >> 32);
                const int within = __builtin_amdgcn_mbcnt_hi(
                                       qhi, __builtin_amdgcn_mbcnt_lo(qlo, 0));
                const int pos = C + within;
                if (pos < 256) scomp[wid * CAPS + pos] = p[k];
            }
            C += (int)__popcll(mk);
        }
    }

    __builtin_amdgcn_s_waitcnt(0);             // drain ds_writes (same wave)
    const int Cc = (C < 256) ? C : 256;
    float cp[4];                                // invalid slots hold 0.0f
    #pragma unroll
    for (int q = 0; q < 4; ++q) {
        const int idx = q * 64 + lane;
        cp[q] = (idx < Cc) ? scomp[wid * CAPS + idx] : 0.0f;
    }

    float pstar, mb = 0.0f;
    int   cnt = 1;
    bool  haveTie;

    if (C > 256) {
        // fallback (rare): keep everything >= sl (off by <=2 boundary elems)
        pstar = (sl > 0.0f) ? __uint_as_float(__float_as_uint(sl) - 1u) : 0.0f;
        haveTie = false;
    } else {
        // ---- Phase C1: fine probes, 2 thresholds per round ----
        float lo_s = sl, hi_s = sh, lo_G = Gl, hi_G = Gh;
        int   lo_C = Cl, hi_C = Ch;
        for (int it = 0; it < 6 && (lo_C - hi_C) > 2; ++it) {
            const float sB = 0.5f * (lo_s + hi_s);
            if (!(sB > lo_s && sB < hi_s)) break;   // ulp-width bracket
            float sA = lo_s + (hi_s - lo_s) *
                       ((lo_G - target) / fmaxf(lo_G - hi_G, 1e-30f));
            if (!(sA > lo_s && sA < hi_s)) sA = sB;
            const float t0 = fminf(sA, sB), t1 = fmaxf(sA, sB); // both > 0

            float a0 = 0.0f, a1 = 0.0f;
            int   k0 = 0,    k1 = 0;
            #pragma unroll
            for (int q = 0; q < 4; ++q) {
                const bool g0 = (cp[q] >= t0);      // cp==0 excluded (t0>0)
                const bool g1 = (cp[q] >= t1);
                a0 += g0 ? cp[q] : 0.0f; k0 += (int)__popcll(__ballot(g0));
                a1 += g1 ? cp[q] : 0.0f; k1 += (int)__popcll(__ballot(g1));
            }
            dppSum2(a0, a1);
            const float M0 = Gh + a0, M1 = Gh + a1;    // M0 >= M1
            const int   D0 = Ch + k0, D1 = Ch + k1;
            if      (M1 >= target) { lo_s = t1; lo_G = M1; lo_C = D1; }
            else if (M0 >= target) { lo_s = t0; lo_G = M0; lo_C = D0;
                                     hi_s = t1; hi_G = M1; hi_C = D1; }
            else                   { hi_s = t0; hi_G = M0; hi_C = D0; }
        }

        // ---- Phase C2: exact distinct-value walk downward from hi_s ----
        float scur = hi_s, M = hi_G;
        bool ok = false;
        pstar = lo_s;
        for (int e = 0; e < 16; ++e) {
            float v0 = 0.0f, v1 = 0.0f;
            #pragma unroll
            for (int q = 0; q < 4; q += 2) {
                v0 = fmaxf(v0, (cp[q]     < scur) ? cp[q]     : 0.0f);
                v1 = fmaxf(v1, (cp[q + 1] < scur) ? cp[q + 1] : 0.0f);
            }
            const float v = dppMax(fmaxf(v0, v1));
            if (!(v > 0.0f)) break;            // fp knife-edge; fallback
            int cvn = 0;
            #pragma unroll
            for (int q = 0; q < 4; ++q)
                cvn += (int)__popcll(__ballot(cp[q] == v));  // v>0: 0 never ties
            const float Mn = M + v * (float)cvn;  // exact: ties bit-identical
            if (Mn >= target) { pstar = v; mb = M; cnt = cvn; ok = true; break; }
            M = Mn; scur = v;
        }
        haveTie = ok;
        if (!ok) {
            pstar = (lo_s > 0.0f) ? __uint_as_float(__float_as_uint(lo_s) - 1u)
                                  : 0.0f;
        }
    }

    // ---- Phase D: spd = sum_{p > p*} p * (-log p) via select-to-1 ----
    // (order value-critical: unchanged)
    float spd = 0.0f;
    #pragma unroll
    for (int k = 0; k < KPT; ++k) {
        const float t = (p[k] > pstar) ? p[k] : 1.0f;   // log(1) = 0
        spd += t * (-__logf(t));
    }
    spd = dppSum(spd);

    if (lane == 0) {
        float tie = 0.0f;
        if (haveTie) {
            const float R = (target - mb) / pstar;      // exclusive-csum rule
            int q = (int)ceilf(R);
            if (q < 1) q = 1;
            if (q > cnt) q = cnt;
            tie = (float)q * pstar * (-__logf(pstar));
        }
        wacc[wid] = (spd + tie) / Z;
    }
    __syncthreads();                     // all waves reach exactly once
    if (tid == 0) {
        const float v = wacc[0] + wacc[1] + wacc[2] + wacc[3];
        if (partial) partial[blockIdx.x] = v;   // no same-address atomic
        else         atomicAdd(out, v);         // ws_size fallback
    }
}

// Deterministic 2nd-stage reduce: nblocks (<=4096) floats -> out[0].
__global__ __launch_bounds__(1024) void apml_reduce(
        const float* __restrict__ partial, float* __restrict__ out, int n) {
    __shared__ float s[16];
    const int t = threadIdx.x;
    float a = 0.0f;
    #pragma unroll
    for (int q = 0; q < 4; ++q) {
        const int i = t * 4 + q;
        a += (i < n) ? partial[i] : 0.0f;
    }
    a = dppSum(a);
    if ((t & 63) == 0) s[t >> 6] = a;
    __syncthreads();
    if (t == 0) {
        float r = 0.0f;
        #pragma unroll
        for (int w = 0; w < 16; ++w) r += s[w];
        out[0] = r;
    }
}

extern "C" void kernel_launch(void* const* d_in, const int* in_sizes, int n_in,
                              void* d_out, int out_size, void* d_ws, size_t ws_size,
                              hipStream_t stream) {
    const float* x = (const float*)d_in[0];   // [B, N, 3]
    const float* y = (const float*)d_in[1];   // [B, M, 3]
    float* out = (float*)d_out;               // scalar

    const int nrows = in_sizes[0] / 3;        // B * N
    const int nblocks = nrows / WPB;          // 4096

    if (d_ws && ws_size >= (size_t)nblocks * sizeof(float) && nblocks <= 4096) {
        float* partial = (float*)d_ws;
        apml_row_wave<<<nblocks, WPB * 64, 0, stream>>>(x, y, partial, out);
        apml_reduce<<<1, 1024, 0, stream>>>(partial, out, nblocks);
    } else {
        hipMemsetAsync(out, 0, sizeof(float), stream);   // capture-legal
        apml_row_wave<<<nblocks, WPB * 64, 0, stream>>>(x, y, nullptr, out);
    }
}